// Round 6
// baseline (302.314 us; speedup 1.0000x reference)
//
#include <hip/hip_runtime.h>
#include <hip/hip_bf16.h>
#include <hip/hip_cooperative_groups.h>

namespace cg = cooperative_groups;

#define BN 32
#define NPTS 400000
#define NVOX 2560
#define GDYZ 160
#define GDZ 10
#define VN 60
#define PMAX 40
#define CAP 512

/* fused/hist pass geometry */
#define NCH_H 16
#define CHUNK_H (NPTS / NCH_H)   /* 25000, %4 == 0 */
/* legacy list pass geometry (fallback only) */
#define NCH_L 50
#define CHUNK_L (NPTS / NCH_L)   /* 8000, %8 == 0 */

/* ws layout (bytes) */
#define OFF_COUNTS 0
#define SZ_COUNTS (BN * NVOX * 4)                 /* 327680 */
#define OFF_TICKETS (OFF_COUNTS + SZ_COUNTS)
#define SZ_TICKETS (BN * VN * 4)                  /* 7680 */
#define OFF_TOPVOX (OFF_TICKETS + SZ_TICKETS)
#define OFF_TOPCNT (OFF_TOPVOX + BN * VN * 4)
#define OFF_SLOTMAP (OFF_TOPCNT + BN * VN * 4)
#define OFF_LISTS (OFF_SLOTMAP + BN * NVOX)
#define SZ_LISTS (BN * VN * CAP * 4)              /* 3932160 */
#define OFF_VOX (OFF_LISTS + SZ_LISTS)
#define SZ_VOX (BN * NPTS * 2)                    /* 25.6 MB */
#define OFF_PART (OFF_VOX + SZ_VOX)
#define SZ_PART (BN * NCH_H * NVOX * 4)           /* 5.2 MB */

/* out layout (floats) */
#define OUT_PTS 0
#define OUT_VL (BN * VN * PMAX * 3)   /* 230400 */
#define OUT_KC (OUT_VL + BN * VN * 3) /* 236160 */

__device__ __constant__ float KENC[17][5] = {
    {0,0,0,0,1},{0,0,0,1,0},{0,0,0,1,1},{0,0,1,0,0},{0,0,1,0,1},{0,0,1,1,0},
    {0,0,1,1,1},{0,1,0,0,0},{0,1,0,0,1},{0,1,0,1,0},{0,1,0,1,1},{0,1,1,0,0},
    {0,1,1,0,1},{0,1,1,1,0},{0,1,1,1,1},{1,0,0,0,0},{1,0,0,0,1}};

// Exact replica of reference voxelization (IEEE f32 sub + div, trunc).
__device__ __forceinline__ int voxid(float x, float y, float z) {
    float ex = x;
    float ey = __fadd_rn(y, 3.2f);
    float ez = __fadd_rn(z, 2.0f);
    int vx = (int)(ex / 0.4f);
    int vy = (int)(ey / 0.4f);
    int vz = (int)(ez / 0.4f);
    bool valid = !(x == 0.0f && y == 0.0f && z == 0.0f);
    bool inr = (vx >= 0) & (vx < 16) & (vy >= 0) & (vy < 16) & (vz >= 0) & (vz < 10);
    return (valid && inr) ? (vx * GDYZ + vy * GDZ + vz) : 0xFFFF;
}

// ============================ FUSED COOPERATIVE KERNEL ============================
// 512 blocks x 256 threads, 2 blocks/CU (LDS-capped). Phases:
//   1: per-chunk hist (LDS) -> partials; voxel ids cached in LDS (no vox traffic)
//   2: per-batch top-60 (block b*NCH_H), zero tickets, init slotmap, write vl
//   3: build per-(b,slot) index lists from LDS-resident ids
//   4: per-wave: select 40 smallest indices + gather (register-only); kc waves
__global__ __launch_bounds__(256) void k_fused(const float* __restrict__ pc,
        const float* __restrict__ kpts, unsigned int* __restrict__ partials,
        unsigned int* __restrict__ tickets, int* __restrict__ topvox,
        int* __restrict__ topcnt, unsigned char* __restrict__ slotmap,
        unsigned int* __restrict__ lists, float* __restrict__ out) {
    __shared__ unsigned int uhist[NVOX];          // p1 hist / p2 keys / p3 smap+p4 wbuf
    __shared__ unsigned short ids[CHUNK_H];       // p1 -> p3 voxel id cache (50 KB)
    __shared__ unsigned int cand[VN];
    __shared__ unsigned int ncand;
    cg::grid_group grid = cg::this_grid();

    int tid = threadIdx.x;
    int b = blockIdx.x / NCH_H;
    int ch = blockIdx.x % NCH_H;

    // ---------------- phase 1: histogram + id cache ----------------
    for (int v = tid; v < NVOX; v += 256) uhist[v] = 0u;
    __syncthreads();
    {
        const float4* p4 = (const float4*)(pc + ((size_t)b * NPTS + ch * CHUNK_H) * 3);
        for (int lid = tid * 4; lid < CHUNK_H; lid += 256 * 4) {
            int f = (lid * 3) >> 2;  // lid % 4 == 0 -> exact
            float4 q0 = p4[f], q1 = p4[f + 1], q2 = p4[f + 2];
            float xs[4] = {q0.x, q0.w, q1.z, q2.y};
            float ys[4] = {q0.y, q1.x, q1.w, q2.z};
            float zs[4] = {q0.z, q1.y, q2.x, q2.w};
            unsigned short id4[4];
#pragma unroll
            for (int k = 0; k < 4; ++k) {
                int id = voxid(xs[k], ys[k], zs[k]);
                id4[k] = (unsigned short)id;
                if (id < NVOX) atomicAdd(&uhist[id], 1u);
            }
            *(ushort4*)(&ids[lid]) = make_ushort4(id4[0], id4[1], id4[2], id4[3]);
        }
    }
    __syncthreads();
    {
        unsigned int* dst = partials + ((size_t)b * NCH_H + ch) * NVOX;
        for (int v = tid; v < NVOX; v += 256) dst[v] = uhist[v];
    }
    grid.sync();

    // ---------------- phase 2: per-batch top-60 (one block per batch) ----------------
    if (ch == 0) {
        unsigned int* keys = uhist;
#pragma unroll
        for (int k = 0; k < NVOX / 256; ++k) {   // 10 voxels/thread
            int v = tid + 256 * k;
            const unsigned int* src = partials + (size_t)b * NCH_H * NVOX + v;
            unsigned int s = 0;
#pragma unroll
            for (int c = 0; c < NCH_H; ++c) s += src[(size_t)c * NVOX];
            keys[v] = (s << 12) | (unsigned int)(4095 - v);
        }
        {   // slotmap = 0xFF via u32 stores
            unsigned int* d32 = (unsigned int*)(slotmap + b * NVOX);
            for (int w = tid; w < NVOX / 4; w += 256) d32[w] = 0xFFFFFFFFu;
        }
        if (tid < VN) tickets[b * VN + tid] = 0u;
        if (tid == 0) ncand = 0u;
        __syncthreads();
        if (tid < 64) {
            unsigned int kr[NVOX / 64];          // 40 keys/lane, static idx
#pragma unroll
            for (int j = 0; j < NVOX / 64; ++j) kr[j] = keys[tid + 64 * j];
            // binary search: largest T with count(keys >= T) >= 60
            unsigned int lo = 1u, hi = 0x80000000u;
            while (lo < hi) {
                unsigned int mid = lo + ((hi - lo + 1u) >> 1);
                int c = 0;
#pragma unroll
                for (int j = 0; j < NVOX / 64; ++j) c += (kr[j] >= mid) ? 1 : 0;
#pragma unroll
                for (int o = 32; o > 0; o >>= 1) c += __shfl_xor(c, o, 64);
                if (c >= VN) lo = mid; else hi = mid - 1u;
            }
#pragma unroll
            for (int j = 0; j < NVOX / 64; ++j) {
                if (kr[j] >= lo) {
                    unsigned int p = atomicAdd(&ncand, 1u);
                    cand[p] = kr[j];
                }
            }
            if (tid < VN) {                      // rank & write (same wave)
                unsigned int ki = cand[tid];
                int r = 0;
                for (int j = 0; j < VN; ++j) r += (cand[j] > ki) ? 1 : 0;
                int v = 4095 - (int)(ki & 4095u);
                topvox[b * VN + r] = v;
                topcnt[b * VN + r] = (int)(ki >> 12);
                slotmap[b * NVOX + v] = (unsigned char)r;
                int vx = v / GDYZ, rem = v % GDYZ, vy = rem / GDZ, vz = rem % GDZ;
                float c0 = __fadd_rn(__fmul_rn((float)vx, 0.4f), 0.2f);
                float c1 = __fadd_rn(__fadd_rn(-3.2f, __fmul_rn((float)vy, 0.4f)), 0.2f);
                float c2 = __fadd_rn(__fadd_rn(-2.0f, __fmul_rn((float)vz, 0.4f)), 0.2f);
                float* vl = out + OUT_VL + (b * VN + r) * 3;
                vl[0] = c0; vl[1] = c1; vl[2] = c2;
            }
        }
    }
    grid.sync();

    // ---------------- phase 3: build lists from LDS ids ----------------
    {
        unsigned char* smap = (unsigned char*)uhist;   // keys dead now
        const unsigned int* s32 = (const unsigned int*)(slotmap + b * NVOX);
        unsigned int* d32 = (unsigned int*)smap;
        for (int v = tid; v < NVOX / 4; v += 256) d32[v] = s32[v];
        __syncthreads();
        int gbase = ch * CHUNK_H;
        for (int lid = tid * 4; lid < CHUNK_H; lid += 256 * 4) {
            ushort4 w4 = *(const ushort4*)(&ids[lid]);
            unsigned short id4[4] = {w4.x, w4.y, w4.z, w4.w};
#pragma unroll
            for (int k = 0; k < 4; ++k) {
                if (id4[k] < NVOX) {
                    unsigned char s = smap[id4[k]];
                    if (s != 0xFF) {
                        unsigned int t = atomicAdd(&tickets[b * VN + s], 1u);
                        if (t < CAP) lists[(size_t)(b * VN + s) * CAP + t] =
                                         (unsigned int)(gbase + lid + k);
                    }
                }
            }
        }
    }
    grid.sync();

    // ---------------- phase 4: select+gather / kc (one wave each) ----------------
    {
        int w = blockIdx.x * 4 + (tid >> 6);
        int lane = tid & 63;
        unsigned int* wbuf = uhist + 640 + (tid >> 6) * PMAX;  // fallback only
        if (w < BN * VN) {
            int bs = w, bb = bs / VN;
            int cnt = topcnt[bs];
            float* po = out + OUT_PTS + (size_t)bs * PMAX * 3;
            if (cnt == 0) {
                if (lane < PMAX * 3) po[lane] = 0.0f;
                if (lane + 64 < PMAX * 3) po[lane + 64] = 0.0f;
            } else {
                int K = cnt < PMAX ? cnt : PMAX;
                int t1 = lane, t2 = lane + 64;
                int j1 = t1 / 3;
                int j2 = (t2 < PMAX * 3) ? (t2 / 3) : 0;
                int jj1 = (cnt >= PMAX) ? j1 : (j1 % cnt);
                int jj2 = (cnt >= PMAX) ? j2 : (j2 % cnt);
                unsigned int s1 = 0u, s2 = 0u;
                if (cnt <= CAP) {
                    const unsigned int* L = lists + (size_t)bs * CAP;
                    unsigned int vals[CAP / 64];
#pragma unroll
                    for (int q = 0; q < CAP / 64; ++q) {
                        int e = lane + q * 64;
                        vals[q] = (e < cnt) ? L[e] : 0xFFFFFFFFu;
                    }
                    unsigned int lastp = 0u;
                    for (int r = 0; r < K; ++r) {
                        unsigned int m = 0xFFFFFFFFu;
#pragma unroll
                        for (int q = 0; q < CAP / 64; ++q) {
                            unsigned int v = vals[q];
                            if (v >= lastp && v < m) m = v;
                        }
#pragma unroll
                        for (int o = 32; o > 0; o >>= 1) {
                            unsigned int t = __shfl_xor(m, o, 64);
                            m = (t < m) ? t : m;
                        }
                        if (r == jj1) s1 = m;    // m is wave-uniform
                        if (r == jj2) s2 = m;
                        lastp = m + 1u;
                    }
                } else {
                    // rare path: ordered single-wave scan of the whole batch
                    const float* pb = pc + (size_t)bb * NPTS * 3;
                    int v = topvox[bs];
                    int k = 0;
                    for (int base = 0; base < NPTS && k < PMAX; base += 64) {
                        int i = base + lane;
                        int id = voxid(pb[i * 3], pb[i * 3 + 1], pb[i * 3 + 2]);
                        unsigned long long mask = __ballot(id == v);
                        if (id == v) {
                            int rk = k + (int)__popcll(mask & ((1ull << lane) - 1ull));
                            if (rk < PMAX) wbuf[rk] = (unsigned int)i;
                        }
                        k += (int)__popcll(mask);
                    }
                    __threadfence_block();
                    s1 = wbuf[jj1];
                    s2 = wbuf[jj2];
                }
                po[t1] = pc[((size_t)bb * NPTS + s1) * 3 + (t1 % 3)];
                if (t2 < PMAX * 3)
                    po[t2] = pc[((size_t)bb * NPTS + s2) * 3 + (t2 % 3)];
            }
        } else if (w < BN * VN + BN) {
            int bb = w - BN * VN;
            // lane i<60 holds vl row i
            float v0 = 0.f, v1 = 0.f, v2 = 0.f;
            if (lane < VN) {
                const float* vl = out + OUT_VL + (bb * VN + lane) * 3;
                v0 = vl[0]; v1 = vl[1]; v2 = vl[2];
            }
            float a0 = 0.f, a1 = 0.f, a2 = 0.f;
            if (lane < 17) {
                const float* kp = kpts + bb * 17 * 3 + lane * 3;
                a0 = kp[2]; a1 = kp[0]; a2 = kp[1];    // kq = kpts[:, [2,0,1]]
            }
            float best = 1e30f;
            int bi = 0;
            for (int i = 0; i < VN; ++i) {
                float w0 = __shfl(v0, i, 64), w1 = __shfl(v1, i, 64),
                      w2 = __shfl(v2, i, 64);
                float d0 = __fsub_rn(a0, w0);
                float d1 = __fsub_rn(a1, w1);
                float d2 = __fsub_rn(a2, w2);
                float sq = __fadd_rn(__fadd_rn(__fmul_rn(d0, d0), __fmul_rn(d1, d1)),
                                     __fmul_rn(d2, d2));
                float d = __fsqrt_rn(sq);
                if (d < best) { best = d; bi = i; }
            }
            // lane i<60 holds kc row i; sequential 17-step update, broadcast by shfl
            float r0 = 0.f, r1 = 0.f, r2 = 0.f, r3 = 0.f, r4 = 0.f, r5 = 0.f;
            for (int j = 0; j < 17; ++j) {
                float mdj = __shfl(best, j, 64);
                int mij = __shfl(bi, j, 64);
                if (lane == mij) {
                    bool z = (r0 == 0.f) && (r1 == 0.f) && (r2 == 0.f) &&
                             (r3 == 0.f) && (r4 == 0.f) && (r5 == 0.f);
                    float e0 = KENC[j][0], e1 = KENC[j][1], e2 = KENC[j][2],
                          e3 = KENC[j][3], e4 = KENC[j][4], e5 = mdj;
                    r0 = z ? e0 : __fmul_rn(__fadd_rn(r0, e0), 0.5f);
                    r1 = z ? e1 : __fmul_rn(__fadd_rn(r1, e1), 0.5f);
                    r2 = z ? e2 : __fmul_rn(__fadd_rn(r2, e2), 0.5f);
                    r3 = z ? e3 : __fmul_rn(__fadd_rn(r3, e3), 0.5f);
                    r4 = z ? e4 : __fmul_rn(__fadd_rn(r4, e4), 0.5f);
                    r5 = z ? e5 : __fmul_rn(__fadd_rn(r5, e5), 0.5f);
                }
            }
            if (lane < VN) {
                float* kc = out + OUT_KC + (bb * VN + lane) * 6;
                kc[0] = r0; kc[1] = r1; kc[2] = r2;
                kc[3] = r3; kc[4] = r4; kc[5] = r5;
            }
        }
    }
}

// ============================ LEGACY FALLBACK KERNELS ============================
__global__ __launch_bounds__(256) void k_vox_hist(const float* __restrict__ pc,
        unsigned int* __restrict__ counts, unsigned short* __restrict__ vox,
        unsigned int* __restrict__ partials, int useVox, int usePart) {
    __shared__ unsigned int hist[NVOX];
    int b = blockIdx.x / NCH_H;
    int ch = blockIdx.x % NCH_H;
    for (int v = threadIdx.x; v < NVOX; v += 256) hist[v] = 0u;
    __syncthreads();
    const float4* p4 = (const float4*)(pc + (size_t)b * NPTS * 3);
    int start = ch * CHUNK_H, end = start + CHUNK_H;
    for (int g = start + threadIdx.x * 4; g < end; g += 256 * 4) {
        int f = (g * 3) >> 2;
        float4 q0 = p4[f], q1 = p4[f + 1], q2 = p4[f + 2];
        float xs[4] = {q0.x, q0.w, q1.z, q2.y};
        float ys[4] = {q0.y, q1.x, q1.w, q2.z};
        float zs[4] = {q0.z, q1.y, q2.x, q2.w};
        unsigned short id4[4];
#pragma unroll
        for (int k = 0; k < 4; ++k) {
            int id = voxid(xs[k], ys[k], zs[k]);
            id4[k] = (unsigned short)id;
            if (id < NVOX) atomicAdd(&hist[id], 1u);
        }
        if (useVox)
            *(ushort4*)(&vox[(size_t)b * NPTS + g]) =
                make_ushort4(id4[0], id4[1], id4[2], id4[3]);
    }
    __syncthreads();
    if (usePart) {
        unsigned int* dst = partials + ((size_t)b * NCH_H + ch) * NVOX;
        for (int v = threadIdx.x; v < NVOX; v += 256) dst[v] = hist[v];
    } else {
        for (int v = threadIdx.x; v < NVOX; v += 256) {
            unsigned int c = hist[v];
            if (c) atomicAdd(&counts[b * NVOX + v], c);
        }
    }
}

__global__ __launch_bounds__(256) void k_topk(
        const unsigned int* __restrict__ partials,
        const unsigned int* __restrict__ counts, int usePart,
        int* __restrict__ topvox, int* __restrict__ topcnt,
        unsigned char* __restrict__ slotmap, unsigned int* __restrict__ tickets,
        float* __restrict__ out) {
    __shared__ unsigned int keys[NVOX];
    __shared__ unsigned int cand[VN];
    __shared__ unsigned int ncand;
    int b = blockIdx.x;
    int tid = threadIdx.x;
    if (usePart) {
#pragma unroll
        for (int k = 0; k < NVOX / 256; ++k) {
            int v = tid + 256 * k;
            const unsigned int* src = partials + (size_t)b * NCH_H * NVOX + v;
            unsigned int s = 0;
#pragma unroll
            for (int c = 0; c < NCH_H; ++c) s += src[(size_t)c * NVOX];
            keys[v] = (s << 12) | (unsigned int)(4095 - v);
        }
    } else {
        for (int v = tid; v < NVOX; v += 256)
            keys[v] = (counts[b * NVOX + v] << 12) | (unsigned int)(4095 - v);
    }
    {
        unsigned int* d32 = (unsigned int*)(slotmap + b * NVOX);
        for (int w = tid; w < NVOX / 4; w += 256) d32[w] = 0xFFFFFFFFu;
    }
    if (tid < VN) tickets[b * VN + tid] = 0u;
    if (tid == 0) ncand = 0u;
    __syncthreads();
    if (tid < 64) {
        unsigned int kr[NVOX / 64];
#pragma unroll
        for (int j = 0; j < NVOX / 64; ++j) kr[j] = keys[tid + 64 * j];
        unsigned int lo = 1u, hi = 0x80000000u;
        while (lo < hi) {
            unsigned int mid = lo + ((hi - lo + 1u) >> 1);
            int c = 0;
#pragma unroll
            for (int j = 0; j < NVOX / 64; ++j) c += (kr[j] >= mid) ? 1 : 0;
#pragma unroll
            for (int o = 32; o > 0; o >>= 1) c += __shfl_xor(c, o, 64);
            if (c >= VN) lo = mid; else hi = mid - 1u;
        }
#pragma unroll
        for (int j = 0; j < NVOX / 64; ++j) {
            if (kr[j] >= lo) {
                unsigned int p = atomicAdd(&ncand, 1u);
                cand[p] = kr[j];
            }
        }
        if (tid < VN) {
            unsigned int ki = cand[tid];
            int r = 0;
            for (int j = 0; j < VN; ++j) r += (cand[j] > ki) ? 1 : 0;
            int v = 4095 - (int)(ki & 4095u);
            topvox[b * VN + r] = v;
            topcnt[b * VN + r] = (int)(ki >> 12);
            slotmap[b * NVOX + v] = (unsigned char)r;
            int vx = v / GDYZ, rem = v % GDYZ, vy = rem / GDZ, vz = rem % GDZ;
            float c0 = __fadd_rn(__fmul_rn((float)vx, 0.4f), 0.2f);
            float c1 = __fadd_rn(__fadd_rn(-3.2f, __fmul_rn((float)vy, 0.4f)), 0.2f);
            float c2 = __fadd_rn(__fadd_rn(-2.0f, __fmul_rn((float)vz, 0.4f)), 0.2f);
            float* vl = out + OUT_VL + (b * VN + r) * 3;
            vl[0] = c0; vl[1] = c1; vl[2] = c2;
        }
    }
}

__global__ __launch_bounds__(256) void k_build_lists(const float* __restrict__ pc,
        const unsigned short* __restrict__ vox, int useVox,
        const unsigned char* __restrict__ slotmap,
        unsigned int* __restrict__ tickets, unsigned int* __restrict__ lists) {
    __shared__ unsigned char smap[NVOX];
    int b = blockIdx.x / NCH_L;
    int ch = blockIdx.x % NCH_L;
    {
        const unsigned int* s32 = (const unsigned int*)(slotmap + b * NVOX);
        unsigned int* d32 = (unsigned int*)smap;
        for (int v = threadIdx.x; v < NVOX / 4; v += 256) d32[v] = s32[v];
    }
    __syncthreads();
    int start = ch * CHUNK_L, end = start + CHUNK_L;
    if (useVox) {
        const unsigned short* vb = vox + (size_t)b * NPTS;
        for (int i = start + threadIdx.x * 8; i < end; i += 256 * 8) {
            uint4 w = *(const uint4*)(vb + i);
            unsigned int id8[8] = {w.x & 0xFFFFu, w.x >> 16, w.y & 0xFFFFu, w.y >> 16,
                                   w.z & 0xFFFFu, w.z >> 16, w.w & 0xFFFFu, w.w >> 16};
#pragma unroll
            for (int k = 0; k < 8; ++k) {
                if (id8[k] < NVOX) {
                    unsigned char s = smap[id8[k]];
                    if (s != 0xFF) {
                        unsigned int t = atomicAdd(&tickets[b * VN + s], 1u);
                        if (t < CAP) lists[(size_t)(b * VN + s) * CAP + t] =
                                         (unsigned int)(i + k);
                    }
                }
            }
        }
    } else {
        const float* pb = pc + (size_t)b * NPTS * 3;
        for (int i = start + threadIdx.x; i < end; i += 256) {
            int id = voxid(pb[i * 3], pb[i * 3 + 1], pb[i * 3 + 2]);
            if (id < NVOX) {
                unsigned char s = smap[id];
                if (s != 0xFF) {
                    unsigned int t = atomicAdd(&tickets[b * VN + s], 1u);
                    if (t < CAP) lists[(size_t)(b * VN + s) * CAP + t] = (unsigned int)i;
                }
            }
        }
    }
}

__global__ __launch_bounds__(64) void k_select_kc(const float* __restrict__ pc,
        const float* __restrict__ kpts,
        const int* __restrict__ topvox, const int* __restrict__ topcnt,
        const unsigned int* __restrict__ lists, float* __restrict__ out) {
    __shared__ unsigned int sorted[PMAX];
    __shared__ float vl_s[VN * 3];
    __shared__ float kc_s[VN * 6];
    __shared__ float md_s[17];
    __shared__ int mi_s[17];
    int bs = blockIdx.x;
    int lane = threadIdx.x;

    if (bs >= BN * VN) {
        int b = bs - BN * VN;
        const float* vl = out + OUT_VL + b * VN * 3;
        for (int i = lane; i < VN * 3; i += 64) vl_s[i] = vl[i];
        for (int i = lane; i < VN * 6; i += 64) kc_s[i] = 0.0f;
        __syncthreads();
        if (lane < 17) {
            const float* kp = kpts + b * 17 * 3 + lane * 3;
            float a0 = kp[2], a1 = kp[0], a2 = kp[1];
            float best = 1e30f;
            int bi = 0;
            for (int i = 0; i < VN; ++i) {
                float d0 = __fsub_rn(a0, vl_s[i * 3 + 0]);
                float d1 = __fsub_rn(a1, vl_s[i * 3 + 1]);
                float d2 = __fsub_rn(a2, vl_s[i * 3 + 2]);
                float sq = __fadd_rn(__fadd_rn(__fmul_rn(d0, d0), __fmul_rn(d1, d1)),
                                     __fmul_rn(d2, d2));
                float d = __fsqrt_rn(sq);
                if (d < best) { best = d; bi = i; }
            }
            md_s[lane] = best;
            mi_s[lane] = bi;
        }
        __syncthreads();
        if (lane == 0) {
            for (int j = 0; j < 17; ++j) {
                float e[6] = {KENC[j][0], KENC[j][1], KENC[j][2], KENC[j][3],
                              KENC[j][4], md_s[j]};
                float* row = kc_s + mi_s[j] * 6;
                bool z = true;
                for (int q = 0; q < 6; ++q) z = z && (row[q] == 0.0f);
                for (int q = 0; q < 6; ++q)
                    row[q] = z ? e[q] : __fmul_rn(__fadd_rn(row[q], e[q]), 0.5f);
            }
        }
        __syncthreads();
        float* kc = out + OUT_KC + b * VN * 6;
        for (int i = lane; i < VN * 6; i += 64) kc[i] = kc_s[i];
        return;
    }

    int b = bs / VN;
    int cnt = topcnt[bs];
    float* po = out + OUT_PTS + (size_t)bs * PMAX * 3;
    if (cnt == 0) {
        for (int t = lane; t < PMAX * 3; t += 64) po[t] = 0.0f;
        return;
    }
    int K = cnt < PMAX ? cnt : PMAX;
    if (cnt <= CAP) {
        const unsigned int* L = lists + (size_t)bs * CAP;
        unsigned int vals[CAP / 64];
#pragma unroll
        for (int q = 0; q < CAP / 64; ++q) {
            int e = lane + q * 64;
            vals[q] = (e < cnt) ? L[e] : 0xFFFFFFFFu;
        }
        unsigned int lastp = 0u;
        for (int r = 0; r < K; ++r) {
            unsigned int m = 0xFFFFFFFFu;
#pragma unroll
            for (int q = 0; q < CAP / 64; ++q) {
                unsigned int v = vals[q];
                if (v >= lastp && v < m) m = v;
            }
#pragma unroll
            for (int o = 32; o > 0; o >>= 1) {
                unsigned int t = __shfl_xor(m, o, 64);
                m = (t < m) ? t : m;
            }
            if (lane == 0) sorted[r] = m;
            lastp = m + 1u;
        }
    } else {
        const float* pb = pc + (size_t)b * NPTS * 3;
        int v = topvox[bs];
        int k = 0;
        for (int base = 0; base < NPTS && k < PMAX; base += 64) {
            int i = base + lane;
            int id = voxid(pb[i * 3], pb[i * 3 + 1], pb[i * 3 + 2]);
            unsigned long long mask = __ballot(id == v);
            if (id == v) {
                int rk = k + (int)__popcll(mask & ((1ull << lane) - 1ull));
                if (rk < PMAX) sorted[rk] = (unsigned int)i;
            }
            k += (int)__popcll(mask);
        }
    }
    __syncthreads();
    for (int t = lane; t < PMAX * 3; t += 64) {
        int j = t / 3, kk = t % 3;
        int jj = (cnt >= PMAX) ? j : (j % cnt);
        unsigned int idx = sorted[jj];
        po[t] = pc[((size_t)b * NPTS + idx) * 3 + kk];
    }
}

extern "C" void kernel_launch(void* const* d_in, const int* in_sizes, int n_in,
                              void* d_out, int out_size, void* d_ws, size_t ws_size,
                              hipStream_t stream) {
    const float* pc = (const float*)d_in[0];
    const float* kpts = (const float*)d_in[1];
    float* out = (float*)d_out;
    char* ws = (char*)d_ws;

    unsigned int* counts = (unsigned int*)(ws + OFF_COUNTS);
    unsigned int* tickets = (unsigned int*)(ws + OFF_TICKETS);
    int* topvox = (int*)(ws + OFF_TOPVOX);
    int* topcnt = (int*)(ws + OFF_TOPCNT);
    unsigned char* slotmap = (unsigned char*)(ws + OFF_SLOTMAP);
    unsigned int* lists = (unsigned int*)(ws + OFF_LISTS);
    unsigned short* vox = (unsigned short*)(ws + OFF_VOX);
    unsigned int* partials = (unsigned int*)(ws + OFF_PART);
    int useVox = (ws_size >= (size_t)OFF_PART) ? 1 : 0;
    int usePart = (ws_size >= (size_t)(OFF_PART + SZ_PART)) ? 1 : 0;

    hipError_t cerr = hipErrorUnknown;
    if (usePart) {
        void* kargs[] = {(void*)&pc, (void*)&kpts, (void*)&partials,
                         (void*)&tickets, (void*)&topvox, (void*)&topcnt,
                         (void*)&slotmap, (void*)&lists, (void*)&out};
        cerr = hipLaunchCooperativeKernel((const void*)k_fused,
                                          dim3(BN * NCH_H), dim3(256),
                                          kargs, 0, stream);
    }
    if (cerr == hipSuccess) return;

    // -------- fallback: the proven 4-kernel chain --------
    if (!usePart)
        hipMemsetAsync(ws + OFF_COUNTS, 0, SZ_COUNTS, stream);
    hipLaunchKernelGGL(k_vox_hist, dim3(BN * NCH_H), dim3(256), 0, stream,
                       pc, counts, vox, partials, useVox, usePart);
    hipLaunchKernelGGL(k_topk, dim3(BN), dim3(256), 0, stream,
                       partials, counts, usePart, topvox, topcnt, slotmap,
                       tickets, out);
    hipLaunchKernelGGL(k_build_lists, dim3(BN * NCH_L), dim3(256), 0, stream,
                       pc, vox, useVox, slotmap, tickets, lists);
    hipLaunchKernelGGL(k_select_kc, dim3(BN * VN + BN), dim3(64), 0, stream,
                       pc, kpts, topvox, topcnt, lists, out);
}

// Round 7
// 130.591 us; speedup vs baseline: 2.3150x; 2.3150x over previous
//
#include <hip/hip_runtime.h>
#include <hip/hip_bf16.h>

#define BN 32
#define NPTS 400000
#define NVOX 2560
#define GDYZ 160
#define GDZ 10
#define VN 60
#define PMAX 40
#define CAP 512

/* hist pass geometry */
#define NCH_H 16
#define CHUNK_H (NPTS / NCH_H)   /* 25000, %4 == 0 */
/* list pass geometry */
#define NCH_L 50
#define CHUNK_L (NPTS / NCH_L)   /* 8000, %8 == 0 */

/* ws layout (bytes) */
#define OFF_COUNTS 0
#define SZ_COUNTS (BN * NVOX * 4)                 /* 327680 */
#define OFF_TICKETS (OFF_COUNTS + SZ_COUNTS)
#define SZ_TICKETS (BN * VN * 4)                  /* 7680 */
#define OFF_TOPVOX (OFF_TICKETS + SZ_TICKETS)
#define OFF_TOPCNT (OFF_TOPVOX + BN * VN * 4)
#define OFF_SLOTMAP (OFF_TOPCNT + BN * VN * 4)
#define OFF_LISTS (OFF_SLOTMAP + BN * NVOX)
#define SZ_LISTS (BN * VN * CAP * 4)              /* 3932160 */
#define OFF_VOX (OFF_LISTS + SZ_LISTS)
#define SZ_VOX (BN * NPTS * 2)                    /* 25.6 MB */
#define OFF_PART (OFF_VOX + SZ_VOX)
#define SZ_PART (BN * NCH_H * NVOX * 4)           /* 5.2 MB */

/* out layout (floats) */
#define OUT_PTS 0
#define OUT_VL (BN * VN * PMAX * 3)   /* 230400 */
#define OUT_KC (OUT_VL + BN * VN * 3) /* 236160 */

__device__ __constant__ float KENC[17][5] = {
    {0,0,0,0,1},{0,0,0,1,0},{0,0,0,1,1},{0,0,1,0,0},{0,0,1,0,1},{0,0,1,1,0},
    {0,0,1,1,1},{0,1,0,0,0},{0,1,0,0,1},{0,1,0,1,0},{0,1,0,1,1},{0,1,1,0,0},
    {0,1,1,0,1},{0,1,1,1,0},{0,1,1,1,1},{1,0,0,0,0},{1,0,0,0,1}};

// Exact replica of reference voxelization (IEEE f32 sub + div, trunc).
__device__ __forceinline__ int voxid(float x, float y, float z) {
    float ex = x;
    float ey = __fadd_rn(y, 3.2f);
    float ez = __fadd_rn(z, 2.0f);
    int vx = (int)(ex / 0.4f);
    int vy = (int)(ey / 0.4f);
    int vz = (int)(ez / 0.4f);
    bool valid = !(x == 0.0f && y == 0.0f && z == 0.0f);
    bool inr = (vx >= 0) & (vx < 16) & (vy >= 0) & (vy < 16) & (vz >= 0) & (vz < 10);
    return (valid && inr) ? (vx * GDYZ + vy * GDZ + vz) : 0xFFFF;
}

// Pass 1: voxel-id cache (u16) + per-(batch,chunk) partial histogram.
__global__ __launch_bounds__(256) void k_vox_hist(const float* __restrict__ pc,
        unsigned int* __restrict__ counts, unsigned short* __restrict__ vox,
        unsigned int* __restrict__ partials, int useVox, int usePart) {
    __shared__ unsigned int hist[NVOX];
    int b = blockIdx.x / NCH_H;
    int ch = blockIdx.x % NCH_H;
    for (int v = threadIdx.x; v < NVOX; v += 256) hist[v] = 0u;
    __syncthreads();
    const float4* p4 = (const float4*)(pc + (size_t)b * NPTS * 3);
    int start = ch * CHUNK_H, end = start + CHUNK_H;
    for (int g = start + threadIdx.x * 4; g < end; g += 256 * 4) {
        int f = (g * 3) >> 2;  // g % 4 == 0 -> exact
        float4 q0 = p4[f], q1 = p4[f + 1], q2 = p4[f + 2];
        float xs[4] = {q0.x, q0.w, q1.z, q2.y};
        float ys[4] = {q0.y, q1.x, q1.w, q2.z};
        float zs[4] = {q0.z, q1.y, q2.x, q2.w};
        unsigned short ids[4];
#pragma unroll
        for (int k = 0; k < 4; ++k) {
            int id = voxid(xs[k], ys[k], zs[k]);
            ids[k] = (unsigned short)id;
            if (id < NVOX) atomicAdd(&hist[id], 1u);
        }
        if (useVox)
            *(ushort4*)(&vox[(size_t)b * NPTS + g]) =
                make_ushort4(ids[0], ids[1], ids[2], ids[3]);
    }
    __syncthreads();
    if (usePart) {
        unsigned int* dst = partials + ((size_t)b * NCH_H + ch) * NVOX;
        for (int v = threadIdx.x; v < NVOX; v += 256) dst[v] = hist[v];
    } else {
        for (int v = threadIdx.x; v < NVOX; v += 256) {
            unsigned int c = hist[v];
            if (c) atomicAdd(&counts[b * NVOX + v], c);
        }
    }
}

// Pass 1b+2 fused: per-batch counts reduce + exact top-60 by
// (count desc, index asc) == jax.lax.top_k order.
// Selection: keys are unique u32; binary-search the 60th-largest key,
// collect the exactly-60 keys >= it, rank by pairwise comparison.
__global__ __launch_bounds__(256) void k_topk(
        const unsigned int* __restrict__ partials,
        const unsigned int* __restrict__ counts, int usePart,
        int* __restrict__ topvox, int* __restrict__ topcnt,
        unsigned char* __restrict__ slotmap, unsigned int* __restrict__ tickets,
        float* __restrict__ out) {
    __shared__ unsigned int keys[NVOX];
    __shared__ unsigned int cand[VN];
    __shared__ unsigned int ncand;
    int b = blockIdx.x;
    int tid = threadIdx.x;
    if (usePart) {
#pragma unroll
        for (int k = 0; k < NVOX / 256; ++k) {   // 10 voxels/thread
            int v = tid + 256 * k;
            const unsigned int* src = partials + (size_t)b * NCH_H * NVOX + v;
            unsigned int s = 0;
#pragma unroll
            for (int c = 0; c < NCH_H; ++c) s += src[(size_t)c * NVOX];
            keys[v] = (s << 12) | (unsigned int)(4095 - v);
        }
    } else {
        for (int v = tid; v < NVOX; v += 256)
            keys[v] = (counts[b * NVOX + v] << 12) | (unsigned int)(4095 - v);
    }
    {   // slotmap = 0xFF via u32 stores
        unsigned int* d32 = (unsigned int*)(slotmap + b * NVOX);
        for (int w = tid; w < NVOX / 4; w += 256) d32[w] = 0xFFFFFFFFu;
    }
    if (tid < VN) tickets[b * VN + tid] = 0u;
    if (tid == 0) ncand = 0u;
    __syncthreads();
    if (tid < 64) {
        unsigned int kr[NVOX / 64];              // 40 keys per lane (static idx)
#pragma unroll
        for (int j = 0; j < NVOX / 64; ++j) kr[j] = keys[tid + 64 * j];
        // binary search: largest T with count(keys >= T) >= 60  ->  T = K60
        unsigned int lo = 1u, hi = 0x80000000u;  // keys in [1536, 2^31)
        while (lo < hi) {
            unsigned int mid = lo + ((hi - lo + 1u) >> 1);
            int c = 0;
#pragma unroll
            for (int j = 0; j < NVOX / 64; ++j) c += (kr[j] >= mid) ? 1 : 0;
#pragma unroll
            for (int o = 32; o > 0; o >>= 1) c += __shfl_xor(c, o, 64);
            if (c >= VN) lo = mid; else hi = mid - 1u;
        }
        // collect exactly VN candidates (keys unique => count(>=K60) == 60)
#pragma unroll
        for (int j = 0; j < NVOX / 64; ++j) {
            if (kr[j] >= lo) {
                unsigned int p = atomicAdd(&ncand, 1u);
                cand[p] = kr[j];
            }
        }
        // rank + write outputs (lanes 0..59; same wave, no barrier needed)
        if (tid < VN) {
            unsigned int ki = cand[tid];
            int r = 0;
            for (int j = 0; j < VN; ++j) r += (cand[j] > ki) ? 1 : 0;
            int v = 4095 - (int)(ki & 4095u);
            topvox[b * VN + r] = v;
            topcnt[b * VN + r] = (int)(ki >> 12);
            slotmap[b * NVOX + v] = (unsigned char)r;
            int vx = v / GDYZ, rem = v % GDYZ, vy = rem / GDZ, vz = rem % GDZ;
            float c0 = __fadd_rn(__fmul_rn((float)vx, 0.4f), 0.2f);
            float c1 = __fadd_rn(__fadd_rn(-3.2f, __fmul_rn((float)vy, 0.4f)), 0.2f);
            float c2 = __fadd_rn(__fadd_rn(-2.0f, __fmul_rn((float)vz, 0.4f)), 0.2f);
            float* vl = out + OUT_VL + (b * VN + r) * 3;
            vl[0] = c0; vl[1] = c1; vl[2] = c2;
        }
    }
}

// Pass 2: for each point in a selected voxel, grab a ticket and record index.
__global__ __launch_bounds__(256) void k_build_lists(const float* __restrict__ pc,
        const unsigned short* __restrict__ vox, int useVox,
        const unsigned char* __restrict__ slotmap,
        unsigned int* __restrict__ tickets, unsigned int* __restrict__ lists) {
    __shared__ unsigned char smap[NVOX];
    int b = blockIdx.x / NCH_L;
    int ch = blockIdx.x % NCH_L;
    {
        const unsigned int* s32 = (const unsigned int*)(slotmap + b * NVOX);
        unsigned int* d32 = (unsigned int*)smap;
        for (int v = threadIdx.x; v < NVOX / 4; v += 256) d32[v] = s32[v];
    }
    __syncthreads();
    int start = ch * CHUNK_L, end = start + CHUNK_L;
    if (useVox) {
        const unsigned short* vb = vox + (size_t)b * NPTS;
        for (int i = start + threadIdx.x * 8; i < end; i += 256 * 8) {
            uint4 w = *(const uint4*)(vb + i);
            unsigned int ids[8] = {w.x & 0xFFFFu, w.x >> 16, w.y & 0xFFFFu, w.y >> 16,
                                   w.z & 0xFFFFu, w.z >> 16, w.w & 0xFFFFu, w.w >> 16};
#pragma unroll
            for (int k = 0; k < 8; ++k) {
                if (ids[k] < NVOX) {
                    unsigned char s = smap[ids[k]];
                    if (s != 0xFF) {
                        unsigned int t = atomicAdd(&tickets[b * VN + s], 1u);
                        if (t < CAP) lists[(size_t)(b * VN + s) * CAP + t] =
                                         (unsigned int)(i + k);
                    }
                }
            }
        }
    } else {
        const float* pb = pc + (size_t)b * NPTS * 3;
        for (int i = start + threadIdx.x; i < end; i += 256) {
            int id = voxid(pb[i * 3], pb[i * 3 + 1], pb[i * 3 + 2]);
            if (id < NVOX) {
                unsigned char s = smap[id];
                if (s != 0xFF) {
                    unsigned int t = atomicAdd(&tickets[b * VN + s], 1u);
                    if (t < CAP) lists[(size_t)(b * VN + s) * CAP + t] = (unsigned int)i;
                }
            }
        }
    }
}

// Pass 3 (merged): blocks [0, BN*VN) = select+gather; blocks [BN*VN, +BN) = kc.
__global__ __launch_bounds__(64) void k_select_kc(const float* __restrict__ pc,
        const float* __restrict__ kpts,
        const int* __restrict__ topvox, const int* __restrict__ topcnt,
        const unsigned int* __restrict__ lists, float* __restrict__ out) {
    __shared__ unsigned int sorted[PMAX];
    __shared__ float vl_s[VN * 3];
    __shared__ float kc_s[VN * 6];
    __shared__ float md_s[17];
    __shared__ int mi_s[17];
    int bs = blockIdx.x;
    int lane = threadIdx.x;

    if (bs >= BN * VN) {
        // ---- keypoint conditioning for batch b ----
        int b = bs - BN * VN;
        const float* vl = out + OUT_VL + b * VN * 3;
        for (int i = lane; i < VN * 3; i += 64) vl_s[i] = vl[i];
        for (int i = lane; i < VN * 6; i += 64) kc_s[i] = 0.0f;
        __syncthreads();
        if (lane < 17) {
            const float* kp = kpts + b * 17 * 3 + lane * 3;
            float a0 = kp[2], a1 = kp[0], a2 = kp[1];  // kq = kpts[:, [2,0,1]]
            float best = 1e30f;
            int bi = 0;
            for (int i = 0; i < VN; ++i) {
                float d0 = __fsub_rn(a0, vl_s[i * 3 + 0]);
                float d1 = __fsub_rn(a1, vl_s[i * 3 + 1]);
                float d2 = __fsub_rn(a2, vl_s[i * 3 + 2]);
                float sq = __fadd_rn(__fadd_rn(__fmul_rn(d0, d0), __fmul_rn(d1, d1)),
                                     __fmul_rn(d2, d2));
                float d = __fsqrt_rn(sq);
                if (d < best) { best = d; bi = i; }
            }
            md_s[lane] = best;
            mi_s[lane] = bi;
        }
        __syncthreads();
        if (lane == 0) {
            for (int j = 0; j < 17; ++j) {
                float e[6] = {KENC[j][0], KENC[j][1], KENC[j][2], KENC[j][3],
                              KENC[j][4], md_s[j]};
                float* row = kc_s + mi_s[j] * 6;
                bool z = true;
                for (int q = 0; q < 6; ++q) z = z && (row[q] == 0.0f);
                for (int q = 0; q < 6; ++q)
                    row[q] = z ? e[q] : __fmul_rn(__fadd_rn(row[q], e[q]), 0.5f);
            }
        }
        __syncthreads();
        float* kc = out + OUT_KC + b * VN * 6;
        for (int i = lane; i < VN * 6; i += 64) kc[i] = kc_s[i];
        return;
    }

    // ---- select 40 smallest indices + cyclic gather ----
    int b = bs / VN;
    int cnt = topcnt[bs];
    float* po = out + OUT_PTS + (size_t)bs * PMAX * 3;
    if (cnt == 0) {
        for (int t = lane; t < PMAX * 3; t += 64) po[t] = 0.0f;
        return;
    }
    int K = cnt < PMAX ? cnt : PMAX;
    if (cnt <= CAP) {
        const unsigned int* L = lists + (size_t)bs * CAP;
        unsigned int vals[CAP / 64];
#pragma unroll
        for (int q = 0; q < CAP / 64; ++q) {
            int e = lane + q * 64;
            vals[q] = (e < cnt) ? L[e] : 0xFFFFFFFFu;
        }
        unsigned int lastp = 0u;
        for (int r = 0; r < K; ++r) {
            unsigned int m = 0xFFFFFFFFu;
#pragma unroll
            for (int q = 0; q < CAP / 64; ++q) {
                unsigned int v = vals[q];
                if (v >= lastp && v < m) m = v;
            }
#pragma unroll
            for (int o = 32; o > 0; o >>= 1) {
                unsigned int t = __shfl_xor(m, o, 64);
                m = (t < m) ? t : m;
            }
            if (lane == 0) sorted[r] = m;
            lastp = m + 1u;
        }
    } else {
        const float* pb = pc + (size_t)b * NPTS * 3;
        int v = topvox[bs];
        int k = 0;
        for (int base = 0; base < NPTS && k < PMAX; base += 64) {
            int i = base + lane;
            int id = voxid(pb[i * 3], pb[i * 3 + 1], pb[i * 3 + 2]);
            unsigned long long mask = __ballot(id == v);
            if (id == v) {
                int rk = k + (int)__popcll(mask & ((1ull << lane) - 1ull));
                if (rk < PMAX) sorted[rk] = (unsigned int)i;
            }
            k += (int)__popcll(mask);
        }
    }
    __syncthreads();
    for (int t = lane; t < PMAX * 3; t += 64) {
        int j = t / 3, kk = t % 3;
        int jj = (cnt >= PMAX) ? j : (j % cnt);
        unsigned int idx = sorted[jj];
        po[t] = pc[((size_t)b * NPTS + idx) * 3 + kk];
    }
}

extern "C" void kernel_launch(void* const* d_in, const int* in_sizes, int n_in,
                              void* d_out, int out_size, void* d_ws, size_t ws_size,
                              hipStream_t stream) {
    const float* pc = (const float*)d_in[0];
    const float* kpts = (const float*)d_in[1];
    float* out = (float*)d_out;
    char* ws = (char*)d_ws;

    unsigned int* counts = (unsigned int*)(ws + OFF_COUNTS);
    unsigned int* tickets = (unsigned int*)(ws + OFF_TICKETS);
    int* topvox = (int*)(ws + OFF_TOPVOX);
    int* topcnt = (int*)(ws + OFF_TOPCNT);
    unsigned char* slotmap = (unsigned char*)(ws + OFF_SLOTMAP);
    unsigned int* lists = (unsigned int*)(ws + OFF_LISTS);
    unsigned short* vox = (unsigned short*)(ws + OFF_VOX);
    unsigned int* partials = (unsigned int*)(ws + OFF_PART);
    int useVox = (ws_size >= (size_t)OFF_PART) ? 1 : 0;
    int usePart = (ws_size >= (size_t)(OFF_PART + SZ_PART)) ? 1 : 0;

    if (!usePart)  // fallback only; primary path never reads counts pre-zeroed
        hipMemsetAsync(ws + OFF_COUNTS, 0, SZ_COUNTS, stream);

    hipLaunchKernelGGL(k_vox_hist, dim3(BN * NCH_H), dim3(256), 0, stream,
                       pc, counts, vox, partials, useVox, usePart);
    hipLaunchKernelGGL(k_topk, dim3(BN), dim3(256), 0, stream,
                       partials, counts, usePart, topvox, topcnt, slotmap,
                       tickets, out);
    hipLaunchKernelGGL(k_build_lists, dim3(BN * NCH_L), dim3(256), 0, stream,
                       pc, vox, useVox, slotmap, tickets, lists);
    hipLaunchKernelGGL(k_select_kc, dim3(BN * VN + BN), dim3(64), 0, stream,
                       pc, kpts, topvox, topcnt, lists, out);
}